// Round 11
// baseline (429.683 us; speedup 1.0000x reference)
//
#include <hip/hip_runtime.h>
#include <hip/hip_bf16.h>

#define N_NODES 100000
#define N_EDGES 1600000

// ---------------- CSR build (1 atomic per edge, packed 64-bit) ----------------

__global__ void init_kernel(unsigned long long* packed) {
    int i = blockIdx.x * 256 + threadIdx.x;
    if (i < N_NODES) packed[i] = 0ULL;
}

// one 64-bit atomic per edge: high 32 = count, low 32 = sum(w * 2^20)
__global__ void count_kernel(const int* __restrict__ ei, const float* __restrict__ w,
                             unsigned long long* packed, int* __restrict__ seq) {
    int e = blockIdx.x * 256 + threadIdx.x;
    if (e < N_EDGES) {
        int c = ei[N_EDGES + e];
        unsigned int fw = (unsigned int)rintf(w[e] * 1048576.0f);
        unsigned long long old = atomicAdd(&packed[c], (1ULL << 32) | (unsigned long long)fw);
        seq[e] = (int)(old >> 32);
    }
}

// per-block exclusive scan over counts (packed>>32); also computes dinv (fused)
__global__ void scanA_kernel(const unsigned long long* __restrict__ packed,
                             int* __restrict__ off, int* __restrict__ bsum,
                             float* __restrict__ dinv) {
    __shared__ int s[1024];
    int t = threadIdx.x;
    int i = blockIdx.x * 1024 + t;
    unsigned long long pk = (i < N_NODES) ? packed[i] : 0ULL;
    int v = (int)(pk >> 32);
    if (i < N_NODES) {
        float deg = 1.0f + (float)(unsigned int)(pk & 0xffffffffULL) * (1.0f / 1048576.0f);
        dinv[i] = rsqrtf(deg);
    }
    s[t] = v; __syncthreads();
    #pragma unroll
    for (int d = 1; d < 1024; d <<= 1) {
        int x = (t >= d) ? s[t - d] : 0;
        __syncthreads();
        s[t] += x;
        __syncthreads();
    }
    if (i < N_NODES) off[i] = s[t] - v;
    if (t == 1023) bsum[blockIdx.x] = s[1023];
}

__global__ void scanB_kernel(int* bsum, int nb) {
    __shared__ int s[1024];
    int t = threadIdx.x;
    int v = (t < nb) ? bsum[t] : 0;
    s[t] = v; __syncthreads();
    #pragma unroll
    for (int d = 1; d < 1024; d <<= 1) {
        int x = (t >= d) ? s[t - d] : 0;
        __syncthreads();
        s[t] += x;
        __syncthreads();
    }
    if (t < nb) bsum[t] = s[t] - v;
}

__global__ void scanC_kernel(int* __restrict__ off, const int* __restrict__ bsum) {
    int i = blockIdx.x * 1024 + threadIdx.x;
    if (i < N_NODES) off[i] += bsum[blockIdx.x];
    if (i == 0) off[N_NODES] = N_EDGES;
}

// atomic-free fill: slot = off[dst] + seq[e]
__global__ void fill_kernel(const int* __restrict__ ei, const float* __restrict__ w,
                            const float* __restrict__ dinv, const int* __restrict__ off,
                            const int* __restrict__ seq, int2* __restrict__ epack) {
    int e = blockIdx.x * 256 + threadIdx.x;
    if (e < N_EDGES) {
        int r = ei[e];
        int c = ei[N_EDGES + e];
        int p = off[c] + seq[e];
        float nrm = dinv[r] * w[e] * dinv[c];
        epack[p] = make_int2(r, __float_as_int(nrm));
    }
}

// ---------------- GEMM1: XW = X @ W1   (100000x128 @ 128x128) ----------------

__global__ __launch_bounds__(256) void gemm1_kernel(const float* __restrict__ X,
                                                    const float* __restrict__ W,
                                                    float* __restrict__ XW) {
    __shared__ float sA[32][132];   // [k][m]
    __shared__ float sB[32][132];   // [k][n] (128 used)
    int t = threadIdx.x;
    int row0 = blockIdx.x * 128;
    int tc = t & 15, tr = t >> 4;
    int m0 = tr * 8, n0 = tc * 8;
    float acc[8][8] = {};
    for (int kt = 0; kt < 128; kt += 32) {
        #pragma unroll
        for (int q = 0; q < 4; ++q) {
            int g = t + q * 256;          // 0..1023
            int row = g >> 3;
            int c4 = g & 7;
            float4 v = make_float4(0.f, 0.f, 0.f, 0.f);
            int grow = row0 + row;
            if (grow < N_NODES) v = *(const float4*)(X + (size_t)grow * 128 + kt + c4 * 4);
            sA[c4 * 4 + 0][row] = v.x;
            sA[c4 * 4 + 1][row] = v.y;
            sA[c4 * 4 + 2][row] = v.z;
            sA[c4 * 4 + 3][row] = v.w;
        }
        #pragma unroll
        for (int q = 0; q < 4; ++q) {
            int g = t + q * 256;
            int k = g >> 5, n4 = g & 31;
            *(float4*)(&sB[k][n4 * 4]) = *(const float4*)(W + (kt + k) * 128 + n4 * 4);
        }
        __syncthreads();
        #pragma unroll
        for (int k = 0; k < 32; ++k) {
            float4 a0 = *(const float4*)(&sA[k][m0]);
            float4 a1 = *(const float4*)(&sA[k][m0 + 4]);
            float4 b0 = *(const float4*)(&sB[k][n0]);
            float4 b1v = *(const float4*)(&sB[k][n0 + 4]);
            float a[8] = {a0.x, a0.y, a0.z, a0.w, a1.x, a1.y, a1.z, a1.w};
            float b[8] = {b0.x, b0.y, b0.z, b0.w, b1v.x, b1v.y, b1v.z, b1v.w};
            #pragma unroll
            for (int j = 0; j < 8; ++j)
                #pragma unroll
                for (int i = 0; i < 8; ++i) acc[j][i] += a[j] * b[i];
        }
        __syncthreads();
    }
    #pragma unroll
    for (int j = 0; j < 8; ++j) {
        int grow = row0 + m0 + j;
        if (grow < N_NODES) {
            float4 v0 = {acc[j][0], acc[j][1], acc[j][2], acc[j][3]};
            float4 v1 = {acc[j][4], acc[j][5], acc[j][6], acc[j][7]};
            *(float4*)(XW + (size_t)grow * 128 + n0) = v0;
            *(float4*)(XW + (size_t)grow * 128 + n0 + 4) = v1;
        }
    }
}

// ---- Fused aggregation-1 + bias + relu + GEMM2 (HW = relu(Anorm@XW + b1) @ W2) ----
// 2 nodes per wave (32 lanes x float4 each); split main(4-deep ILP)/tail loops;
// block-wide GEMM2 tail: 8 nodes x 40 cols = 320 dots over 256 threads.
// Grid = N_NODES/8 = 12500 blocks exactly.

__global__ __launch_bounds__(256) void agg1f_kernel(const float* __restrict__ XW,
                                                    const int* __restrict__ off,
                                                    const int2* __restrict__ epack,
                                                    const float* __restrict__ dinv,
                                                    const float* __restrict__ b1,
                                                    const float* __restrict__ W2,
                                                    float* __restrict__ HW) {
    __shared__ __align__(16) float sW2[5120];   // [k][c] = k*40+c, 20 KB
    __shared__ __align__(16) float sH[8][128];  // 8 H rows (2 per wave)
    int t = threadIdx.x;
    // stage W2 (1280 float4 / 256 threads = 5 each); visible after the barrier below
    #pragma unroll
    for (int q = 0; q < 5; ++q) {
        int g = t + q * 256;
        ((float4*)sW2)[g] = ((const float4*)W2)[g];
    }

    int wv = t >> 6;
    int l = t & 63;
    int half = l >> 5;           // 0: node A, 1: node B
    int lh = l & 31;             // lane within half; features 4*lh..4*lh+3
    int n = blockIdx.x * 8 + wv * 2 + half;
    const float4* XW4 = (const float4*)XW;

    float di = dinv[n];
    float self = di * di;
    float4 v = XW4[(size_t)n * 32 + lh];
    float4 a0, a1, a2, a3;
    a0.x = self * v.x; a0.y = self * v.y; a0.z = self * v.z; a0.w = self * v.w;
    a1 = make_float4(0.f, 0.f, 0.f, 0.f);
    a2 = make_float4(0.f, 0.f, 0.f, 0.f);
    a3 = make_float4(0.f, 0.f, 0.f, 0.f);

    int e0 = off[n], e1 = off[n + 1];
    int emain = e0 + ((e1 - e0) & ~3);
    for (int base = e0; base < emain; base += 4) {
        int2 p0 = epack[base];
        int2 p1 = epack[base + 1];
        int2 p2 = epack[base + 2];
        int2 p3 = epack[base + 3];
        float4 g0 = XW4[(size_t)p0.x * 32 + lh];
        float4 g1 = XW4[(size_t)p1.x * 32 + lh];
        float4 g2 = XW4[(size_t)p2.x * 32 + lh];
        float4 g3 = XW4[(size_t)p3.x * 32 + lh];
        float w0 = __int_as_float(p0.y);
        float w1 = __int_as_float(p1.y);
        float w2 = __int_as_float(p2.y);
        float w3 = __int_as_float(p3.y);
        a0.x += w0 * g0.x; a0.y += w0 * g0.y; a0.z += w0 * g0.z; a0.w += w0 * g0.w;
        a1.x += w1 * g1.x; a1.y += w1 * g1.y; a1.z += w1 * g1.z; a1.w += w1 * g1.w;
        a2.x += w2 * g2.x; a2.y += w2 * g2.y; a2.z += w2 * g2.z; a2.w += w2 * g2.w;
        a3.x += w3 * g3.x; a3.y += w3 * g3.y; a3.z += w3 * g3.z; a3.w += w3 * g3.w;
    }
    for (int e = emain; e < e1; ++e) {
        int2 p = epack[e];
        float w = __int_as_float(p.y);
        float4 g = XW4[(size_t)p.x * 32 + lh];
        a0.x += w * g.x; a0.y += w * g.y; a0.z += w * g.z; a0.w += w * g.w;
    }
    float4 acc;
    acc.x = (a0.x + a1.x) + (a2.x + a3.x);
    acc.y = (a0.y + a1.y) + (a2.y + a3.y);
    acc.z = (a0.z + a1.z) + (a2.z + a3.z);
    acc.w = (a0.w + a1.w) + (a2.w + a3.w);
    float4 bb = ((const float4*)b1)[lh];
    float4 h;
    h.x = fmaxf(acc.x + bb.x, 0.f);
    h.y = fmaxf(acc.y + bb.y, 0.f);
    h.z = fmaxf(acc.z + bb.z, 0.f);
    h.w = fmaxf(acc.w + bb.w, 0.f);
    ((float4*)sH[wv * 2 + half])[lh] = h;
    __syncthreads();   // uniform; also publishes sW2

    // GEMM2 tail: 320 dots flat; HW rows for this block start at blockIdx*320
    float* HWb = HW + (size_t)blockIdx.x * 320;
    {
        int d = t;                       // 0..255
        int node = d / 40;
        int col = d - node * 40;
        const float* hrow = sH[node];
        float dot = 0.f;
        #pragma unroll 4
        for (int k = 0; k < 128; k += 4) {
            float4 h4 = *(const float4*)(hrow + k);
            dot += h4.x * sW2[(k + 0) * 40 + col];
            dot += h4.y * sW2[(k + 1) * 40 + col];
            dot += h4.z * sW2[(k + 2) * 40 + col];
            dot += h4.w * sW2[(k + 3) * 40 + col];
        }
        HWb[d] = dot;
    }
    if (t < 64) {
        int d = 256 + t;
        int node = d / 40;
        int col = d - node * 40;
        const float* hrow = sH[node];
        float dot = 0.f;
        #pragma unroll 4
        for (int k = 0; k < 128; k += 4) {
            float4 h4 = *(const float4*)(hrow + k);
            dot += h4.x * sW2[(k + 0) * 40 + col];
            dot += h4.y * sW2[(k + 1) * 40 + col];
            dot += h4.z * sW2[(k + 2) * 40 + col];
            dot += h4.w * sW2[(k + 3) * 40 + col];
        }
        HWb[d] = dot;
    }
}

// ---------------- Aggregation layer 2 (8-edge ILP, split main/tail) + b2 + softmax ----------------

__global__ __launch_bounds__(256) void agg2_kernel(const float* __restrict__ HW,
                                                   const int* __restrict__ off,
                                                   const int2* __restrict__ epack,
                                                   const float* __restrict__ dinv,
                                                   const float* __restrict__ b2,
                                                   float* __restrict__ out) {
    int n = blockIdx.x * 4 + (threadIdx.x >> 6);
    int l = threadIdx.x & 63;
    if (n >= N_NODES) return;
    bool act = (l < 40);
    int ll = act ? l : l - 40;   // idle lanes mirror low features: loads stay in-row
    float di = dinv[n];
    float acc[8];
    acc[0] = di * di * HW[(size_t)n * 40 + ll];
    #pragma unroll
    for (int k = 1; k < 8; ++k) acc[k] = 0.f;
    int e0 = off[n], e1 = off[n + 1];
    int emain = e0 + ((e1 - e0) & ~7);
    for (int base = e0; base < emain; base += 8) {
        int2 p[8];
        #pragma unroll
        for (int k = 0; k < 8; ++k) p[k] = epack[base + k];
        #pragma unroll
        for (int k = 0; k < 8; ++k) {
            float g = HW[(size_t)p[k].x * 40 + ll];
            acc[k] += __int_as_float(p[k].y) * g;
        }
    }
    for (int e = emain; e < e1; ++e) {
        int2 p = epack[e];
        acc[0] += __int_as_float(p.y) * HW[(size_t)p.x * 40 + ll];
    }
    float a = ((acc[0] + acc[1]) + (acc[2] + acc[3])) + ((acc[4] + acc[5]) + (acc[6] + acc[7]));
    a += b2[ll];
    float m = act ? a : -1e30f;
    #pragma unroll
    for (int d = 32; d; d >>= 1) m = fmaxf(m, __shfl_xor(m, d, 64));
    float pexp = act ? expf(a - m) : 0.f;
    float s = pexp;
    #pragma unroll
    for (int d = 32; d; d >>= 1) s += __shfl_xor(s, d, 64);
    if (act) out[(size_t)n * 40 + l] = pexp / s;
}

// ---------------- launch ----------------

extern "C" void kernel_launch(void* const* d_in, const int* in_sizes, int n_in,
                              void* d_out, int out_size, void* d_ws, size_t ws_size,
                              hipStream_t stream) {
    const float* x  = (const float*)d_in[0];
    const int*   ei = (const int*)d_in[1];
    const float* ew = (const float*)d_in[2];
    // d_in[3] = attention (PERIODS=1 -> softmax = 1.0, unused)
    const float* W1 = (const float*)d_in[4];
    const float* b1 = (const float*)d_in[5];
    const float* W2 = (const float*)d_in[6];
    const float* b2 = (const float*)d_in[7];
    float* out = (float*)d_out;

    char* p = (char*)d_ws;
    auto alloc = [&](size_t bytes) -> void* {
        void* r = (void*)p;
        p += (bytes + 511) & ~(size_t)511;
        return r;
    };
    unsigned long long* packed = (unsigned long long*)alloc((size_t)N_NODES * 8);
    float* dinv   = (float*)alloc((size_t)N_NODES * 4);
    int*   off    = (int*)alloc((size_t)(N_NODES + 1) * 4);
    int*   bsum   = (int*)alloc(1024 * 4);
    int*   seq    = (int*)alloc((size_t)N_EDGES * 4);
    int2*  epack  = (int2*)alloc((size_t)N_EDGES * 8);
    float* XW     = (float*)alloc((size_t)N_NODES * 128 * 4);
    float* HW     = (float*)alloc((size_t)N_NODES * 40 * 4);

    int nblk_n = (N_NODES + 255) / 256;
    int nblk_e = (N_EDGES + 255) / 256;
    int nblk_s = (N_NODES + 1023) / 1024;   // 98

    hipLaunchKernelGGL(init_kernel,  dim3(nblk_n), dim3(256), 0, stream, packed);
    hipLaunchKernelGGL(count_kernel, dim3(nblk_e), dim3(256), 0, stream, ei, ew, packed, seq);
    hipLaunchKernelGGL(scanA_kernel, dim3(nblk_s), dim3(1024), 0, stream, packed, off, bsum, dinv);
    hipLaunchKernelGGL(scanB_kernel, dim3(1), dim3(1024), 0, stream, bsum, nblk_s);
    hipLaunchKernelGGL(scanC_kernel, dim3(nblk_s), dim3(1024), 0, stream, off, bsum);
    hipLaunchKernelGGL(fill_kernel,  dim3(nblk_e), dim3(256), 0, stream, ei, ew, dinv, off, seq, epack);

    hipLaunchKernelGGL(gemm1_kernel, dim3((N_NODES + 127) / 128), dim3(256), 0, stream, x, W1, XW);
    hipLaunchKernelGGL(agg1f_kernel, dim3(N_NODES / 8), dim3(256), 0, stream,
                       XW, off, epack, dinv, b1, W2, HW);
    hipLaunchKernelGGL(agg2_kernel,  dim3((N_NODES + 3) / 4), dim3(256), 0, stream,
                       HW, off, epack, dinv, b2, out);
}

// Round 12
// 375.610 us; speedup vs baseline: 1.1440x; 1.1440x over previous
//
#include <hip/hip_runtime.h>
#include <hip/hip_bf16.h>

#define N_NODES 100000
#define N_EDGES 1600000

// ---------------- CSR build (1 atomic per edge, packed 64-bit) ----------------

__global__ void init_kernel(unsigned long long* packed) {
    int i = blockIdx.x * 256 + threadIdx.x;
    if (i < N_NODES) packed[i] = 0ULL;
}

// one 64-bit atomic per edge: high 32 = count, low 32 = sum(w * 2^20)
__global__ void count_kernel(const int* __restrict__ ei, const float* __restrict__ w,
                             unsigned long long* packed, int* __restrict__ seq) {
    int e = blockIdx.x * 256 + threadIdx.x;
    if (e < N_EDGES) {
        int c = ei[N_EDGES + e];
        unsigned int fw = (unsigned int)rintf(w[e] * 1048576.0f);
        unsigned long long old = atomicAdd(&packed[c], (1ULL << 32) | (unsigned long long)fw);
        seq[e] = (int)(old >> 32);
    }
}

// per-block exclusive scan over counts (packed>>32); also computes dinv (fused)
__global__ void scanA_kernel(const unsigned long long* __restrict__ packed,
                             int* __restrict__ off, int* __restrict__ bsum,
                             float* __restrict__ dinv) {
    __shared__ int s[1024];
    int t = threadIdx.x;
    int i = blockIdx.x * 1024 + t;
    unsigned long long pk = (i < N_NODES) ? packed[i] : 0ULL;
    int v = (int)(pk >> 32);
    if (i < N_NODES) {
        float deg = 1.0f + (float)(unsigned int)(pk & 0xffffffffULL) * (1.0f / 1048576.0f);
        dinv[i] = rsqrtf(deg);
    }
    s[t] = v; __syncthreads();
    #pragma unroll
    for (int d = 1; d < 1024; d <<= 1) {
        int x = (t >= d) ? s[t - d] : 0;
        __syncthreads();
        s[t] += x;
        __syncthreads();
    }
    if (i < N_NODES) off[i] = s[t] - v;
    if (t == 1023) bsum[blockIdx.x] = s[1023];
}

__global__ void scanB_kernel(int* bsum, int nb) {
    __shared__ int s[1024];
    int t = threadIdx.x;
    int v = (t < nb) ? bsum[t] : 0;
    s[t] = v; __syncthreads();
    #pragma unroll
    for (int d = 1; d < 1024; d <<= 1) {
        int x = (t >= d) ? s[t - d] : 0;
        __syncthreads();
        s[t] += x;
        __syncthreads();
    }
    if (t < nb) bsum[t] = s[t] - v;
}

__global__ void scanC_kernel(int* __restrict__ off, const int* __restrict__ bsum) {
    int i = blockIdx.x * 1024 + threadIdx.x;
    if (i < N_NODES) off[i] += bsum[blockIdx.x];
    if (i == 0) off[N_NODES] = N_EDGES;
}

// atomic-free fill: slot = off[dst] + seq[e]
__global__ void fill_kernel(const int* __restrict__ ei, const float* __restrict__ w,
                            const float* __restrict__ dinv, const int* __restrict__ off,
                            const int* __restrict__ seq, int2* __restrict__ epack) {
    int e = blockIdx.x * 256 + threadIdx.x;
    if (e < N_EDGES) {
        int r = ei[e];
        int c = ei[N_EDGES + e];
        int p = off[c] + seq[e];
        float nrm = dinv[r] * w[e] * dinv[c];
        epack[p] = make_int2(r, __float_as_int(nrm));
    }
}

// ---------------- GEMM1: XW = X @ W1   (100000x128 @ 128x128) ----------------

__global__ __launch_bounds__(256) void gemm1_kernel(const float* __restrict__ X,
                                                    const float* __restrict__ W,
                                                    float* __restrict__ XW) {
    __shared__ float sA[32][132];   // [k][m]
    __shared__ float sB[32][132];   // [k][n] (128 used)
    int t = threadIdx.x;
    int row0 = blockIdx.x * 128;
    int tc = t & 15, tr = t >> 4;
    int m0 = tr * 8, n0 = tc * 8;
    float acc[8][8] = {};
    for (int kt = 0; kt < 128; kt += 32) {
        #pragma unroll
        for (int q = 0; q < 4; ++q) {
            int g = t + q * 256;          // 0..1023
            int row = g >> 3;
            int c4 = g & 7;
            float4 v = make_float4(0.f, 0.f, 0.f, 0.f);
            int grow = row0 + row;
            if (grow < N_NODES) v = *(const float4*)(X + (size_t)grow * 128 + kt + c4 * 4);
            sA[c4 * 4 + 0][row] = v.x;
            sA[c4 * 4 + 1][row] = v.y;
            sA[c4 * 4 + 2][row] = v.z;
            sA[c4 * 4 + 3][row] = v.w;
        }
        #pragma unroll
        for (int q = 0; q < 4; ++q) {
            int g = t + q * 256;
            int k = g >> 5, n4 = g & 31;
            *(float4*)(&sB[k][n4 * 4]) = *(const float4*)(W + (kt + k) * 128 + n4 * 4);
        }
        __syncthreads();
        #pragma unroll
        for (int k = 0; k < 32; ++k) {
            float4 a0 = *(const float4*)(&sA[k][m0]);
            float4 a1 = *(const float4*)(&sA[k][m0 + 4]);
            float4 b0 = *(const float4*)(&sB[k][n0]);
            float4 b1v = *(const float4*)(&sB[k][n0 + 4]);
            float a[8] = {a0.x, a0.y, a0.z, a0.w, a1.x, a1.y, a1.z, a1.w};
            float b[8] = {b0.x, b0.y, b0.z, b0.w, b1v.x, b1v.y, b1v.z, b1v.w};
            #pragma unroll
            for (int j = 0; j < 8; ++j)
                #pragma unroll
                for (int i = 0; i < 8; ++i) acc[j][i] += a[j] * b[i];
        }
        __syncthreads();
    }
    #pragma unroll
    for (int j = 0; j < 8; ++j) {
        int grow = row0 + m0 + j;
        if (grow < N_NODES) {
            float4 v0 = {acc[j][0], acc[j][1], acc[j][2], acc[j][3]};
            float4 v1 = {acc[j][4], acc[j][5], acc[j][6], acc[j][7]};
            *(float4*)(XW + (size_t)grow * 128 + n0) = v0;
            *(float4*)(XW + (size_t)grow * 128 + n0 + 4) = v1;
        }
    }
}

// ---- Fused aggregation-1 + bias + relu + GEMM2 (HW = relu(Anorm@XW + b1) @ W2) ----
// r10 structure (wave per node, float2 lanes, 8-edge clamped ILP, per-wave GEMM2 tail)
// + readfirstlane: wave index forced into SGPR so CSR offsets / epack loads / clamps
// run on the SALU+SMEM path; only the gather load + 2 fmacs per edge hit VALU/VMEM.

__global__ __launch_bounds__(256) void agg1f_kernel(const float* __restrict__ XW,
                                                    const int* __restrict__ off,
                                                    const int2* __restrict__ epack,
                                                    const float* __restrict__ dinv,
                                                    const float* __restrict__ b1,
                                                    const float* __restrict__ W2,
                                                    float* __restrict__ HW) {
    __shared__ __align__(16) float sW2[5120];   // [k][c] = k*40+c, 20 KB
    __shared__ __align__(16) float sH[4][128];  // one H row per wave
    int t = threadIdx.x;
    // stage W2 (1280 float4 / 256 threads = 5 each)
    #pragma unroll
    for (int q = 0; q < 5; ++q) {
        int g = t + q * 256;
        ((float4*)sW2)[g] = ((const float4*)W2)[g];
    }

    int wv = __builtin_amdgcn_readfirstlane(t) >> 6;   // SGPR wave index
    int n = blockIdx.x * 4 + wv;                       // uniform node id
    int l = t & 63;
    const float2* XW2 = (const float2*)XW;
    float di = dinv[n];
    float self = di * di;
    float2 v = XW2[(size_t)n * 64 + l];
    float accx[8], accy[8];
    accx[0] = self * v.x; accy[0] = self * v.y;
    #pragma unroll
    for (int k = 1; k < 8; ++k) { accx[k] = 0.f; accy[k] = 0.f; }
    int e0 = off[n], e1 = off[n + 1];                  // scalar loads
    for (int base = e0; base < e1; base += 8) {
        int last = e1 - 1;
        int2 p[8];
        float w[8];
        #pragma unroll
        for (int k = 0; k < 8; ++k) {
            int e = base + k;
            int idx = min(e, last);                    // SALU
            p[k] = epack[idx];                         // scalar load
            w[k] = (e < e1) ? __int_as_float(p[k].y) : 0.f;   // s_cselect
        }
        #pragma unroll
        for (int k = 0; k < 8; ++k) {
            float2 g = XW2[(size_t)p[k].x * 64 + l];   // SGPR base + lane offset
            accx[k] += w[k] * g.x;
            accy[k] += w[k] * g.y;
        }
    }
    float ax = ((accx[0] + accx[1]) + (accx[2] + accx[3])) + ((accx[4] + accx[5]) + (accx[6] + accx[7]));
    float ay = ((accy[0] + accy[1]) + (accy[2] + accy[3])) + ((accy[4] + accy[5]) + (accy[6] + accy[7]));
    float2 bb = ((const float2*)b1)[l];
    float hx = fmaxf(ax + bb.x, 0.f);
    float hy = fmaxf(ay + bb.y, 0.f);
    ((float2*)sH[wv])[l] = make_float2(hx, hy);
    __syncthreads();   // uniform: grid exactly covers N_NODES; also publishes sW2

    // per-wave GEMM2 row: lanes 0..39 each compute one output column
    if (l < 40) {
        const float* hrow = sH[wv];
        float dot = 0.f;
        #pragma unroll 4
        for (int k = 0; k < 128; k += 4) {
            float4 h4 = *(const float4*)(hrow + k);
            dot += h4.x * sW2[(k + 0) * 40 + l];
            dot += h4.y * sW2[(k + 1) * 40 + l];
            dot += h4.z * sW2[(k + 2) * 40 + l];
            dot += h4.w * sW2[(k + 3) * 40 + l];
        }
        HW[(size_t)n * 40 + l] = dot;
    }
}

// ---------------- Aggregation layer 2 (8-edge ILP, scalar CSR path) + b2 + softmax ----------------

__global__ __launch_bounds__(256) void agg2_kernel(const float* __restrict__ HW,
                                                   const int* __restrict__ off,
                                                   const int2* __restrict__ epack,
                                                   const float* __restrict__ dinv,
                                                   const float* __restrict__ b2,
                                                   float* __restrict__ out) {
    int t = threadIdx.x;
    int wv = __builtin_amdgcn_readfirstlane(t) >> 6;   // SGPR wave index
    int n = blockIdx.x * 4 + wv;                       // uniform node id
    int l = t & 63;
    if (n >= N_NODES) return;                          // uniform branch
    bool act = (l < 40);
    int ll = act ? l : l - 40;   // idle lanes mirror low features: loads stay in-row
    float di = dinv[n];
    float acc[8];
    acc[0] = di * di * HW[(size_t)n * 40 + ll];
    #pragma unroll
    for (int k = 1; k < 8; ++k) acc[k] = 0.f;
    int e0 = off[n], e1 = off[n + 1];
    for (int base = e0; base < e1; base += 8) {
        int last = e1 - 1;
        int2 p[8];
        float w[8];
        #pragma unroll
        for (int k = 0; k < 8; ++k) {
            int e = base + k;
            int idx = min(e, last);
            p[k] = epack[idx];
            w[k] = (e < e1) ? __int_as_float(p[k].y) : 0.f;
        }
        #pragma unroll
        for (int k = 0; k < 8; ++k) {
            float g = HW[(size_t)p[k].x * 40 + ll];
            acc[k] += w[k] * g;
        }
    }
    float a = ((acc[0] + acc[1]) + (acc[2] + acc[3])) + ((acc[4] + acc[5]) + (acc[6] + acc[7]));
    a += b2[ll];
    float m = act ? a : -1e30f;
    #pragma unroll
    for (int d = 32; d; d >>= 1) m = fmaxf(m, __shfl_xor(m, d, 64));
    float pexp = act ? expf(a - m) : 0.f;
    float s = pexp;
    #pragma unroll
    for (int d = 32; d; d >>= 1) s += __shfl_xor(s, d, 64);
    if (act) out[(size_t)n * 40 + l] = pexp / s;
}

// ---------------- launch ----------------

extern "C" void kernel_launch(void* const* d_in, const int* in_sizes, int n_in,
                              void* d_out, int out_size, void* d_ws, size_t ws_size,
                              hipStream_t stream) {
    const float* x  = (const float*)d_in[0];
    const int*   ei = (const int*)d_in[1];
    const float* ew = (const float*)d_in[2];
    // d_in[3] = attention (PERIODS=1 -> softmax = 1.0, unused)
    const float* W1 = (const float*)d_in[4];
    const float* b1 = (const float*)d_in[5];
    const float* W2 = (const float*)d_in[6];
    const float* b2 = (const float*)d_in[7];
    float* out = (float*)d_out;

    char* p = (char*)d_ws;
    auto alloc = [&](size_t bytes) -> void* {
        void* r = (void*)p;
        p += (bytes + 511) & ~(size_t)511;
        return r;
    };
    unsigned long long* packed = (unsigned long long*)alloc((size_t)N_NODES * 8);
    float* dinv   = (float*)alloc((size_t)N_NODES * 4);
    int*   off    = (int*)alloc((size_t)(N_NODES + 1) * 4);
    int*   bsum   = (int*)alloc(1024 * 4);
    int*   seq    = (int*)alloc((size_t)N_EDGES * 4);
    int2*  epack  = (int2*)alloc((size_t)N_EDGES * 8);
    float* XW     = (float*)alloc((size_t)N_NODES * 128 * 4);
    float* HW     = (float*)alloc((size_t)N_NODES * 40 * 4);

    int nblk_n = (N_NODES + 255) / 256;
    int nblk_e = (N_EDGES + 255) / 256;
    int nblk_s = (N_NODES + 1023) / 1024;   // 98

    hipLaunchKernelGGL(init_kernel,  dim3(nblk_n), dim3(256), 0, stream, packed);
    hipLaunchKernelGGL(count_kernel, dim3(nblk_e), dim3(256), 0, stream, ei, ew, packed, seq);
    hipLaunchKernelGGL(scanA_kernel, dim3(nblk_s), dim3(1024), 0, stream, packed, off, bsum, dinv);
    hipLaunchKernelGGL(scanB_kernel, dim3(1), dim3(1024), 0, stream, bsum, nblk_s);
    hipLaunchKernelGGL(scanC_kernel, dim3(nblk_s), dim3(1024), 0, stream, off, bsum);
    hipLaunchKernelGGL(fill_kernel,  dim3(nblk_e), dim3(256), 0, stream, ei, ew, dinv, off, seq, epack);

    hipLaunchKernelGGL(gemm1_kernel, dim3((N_NODES + 127) / 128), dim3(256), 0, stream, x, W1, XW);
    hipLaunchKernelGGL(agg1f_kernel, dim3(N_NODES / 4), dim3(256), 0, stream,
                       XW, off, epack, dinv, b1, W2, HW);
    hipLaunchKernelGGL(agg2_kernel,  dim3((N_NODES + 3) / 4), dim3(256), 0, stream,
                       HW, off, epack, dinv, b2, out);
}

// Round 14
// 337.938 us; speedup vs baseline: 1.2715x; 1.1115x over previous
//
#include <hip/hip_runtime.h>
#include <hip/hip_bf16.h>
#include <hip/hip_fp16.h>

#define N_NODES 100000
#define N_EDGES 1600000

// ---------------- CSR build (1 atomic per edge, packed 64-bit) ----------------

__global__ void init_kernel(unsigned long long* packed) {
    int i = blockIdx.x * 256 + threadIdx.x;
    if (i < N_NODES) packed[i] = 0ULL;
}

// one 64-bit atomic per edge: high 32 = count, low 32 = sum(w * 2^20)
__global__ void count_kernel(const int* __restrict__ ei, const float* __restrict__ w,
                             unsigned long long* packed, int* __restrict__ seq) {
    int e = blockIdx.x * 256 + threadIdx.x;
    if (e < N_EDGES) {
        int c = ei[N_EDGES + e];
        unsigned int fw = (unsigned int)rintf(w[e] * 1048576.0f);
        unsigned long long old = atomicAdd(&packed[c], (1ULL << 32) | (unsigned long long)fw);
        seq[e] = (int)(old >> 32);
    }
}

// per-block exclusive scan over counts (packed>>32); also computes dinv (fused)
__global__ void scanA_kernel(const unsigned long long* __restrict__ packed,
                             int* __restrict__ off, int* __restrict__ bsum,
                             float* __restrict__ dinv) {
    __shared__ int s[1024];
    int t = threadIdx.x;
    int i = blockIdx.x * 1024 + t;
    unsigned long long pk = (i < N_NODES) ? packed[i] : 0ULL;
    int v = (int)(pk >> 32);
    if (i < N_NODES) {
        float deg = 1.0f + (float)(unsigned int)(pk & 0xffffffffULL) * (1.0f / 1048576.0f);
        dinv[i] = rsqrtf(deg);
    }
    s[t] = v; __syncthreads();
    #pragma unroll
    for (int d = 1; d < 1024; d <<= 1) {
        int x = (t >= d) ? s[t - d] : 0;
        __syncthreads();
        s[t] += x;
        __syncthreads();
    }
    if (i < N_NODES) off[i] = s[t] - v;
    if (t == 1023) bsum[blockIdx.x] = s[1023];
}

__global__ void scanB_kernel(int* bsum, int nb) {
    __shared__ int s[1024];
    int t = threadIdx.x;
    int v = (t < nb) ? bsum[t] : 0;
    s[t] = v; __syncthreads();
    #pragma unroll
    for (int d = 1; d < 1024; d <<= 1) {
        int x = (t >= d) ? s[t - d] : 0;
        __syncthreads();
        s[t] += x;
        __syncthreads();
    }
    if (t < nb) bsum[t] = s[t] - v;
}

__global__ void scanC_kernel(int* __restrict__ off, const int* __restrict__ bsum) {
    int i = blockIdx.x * 1024 + threadIdx.x;
    if (i < N_NODES) off[i] += bsum[blockIdx.x];
    if (i == 0) off[N_NODES] = N_EDGES;
}

// atomic-free fill: slot = off[dst] + seq[e]
__global__ void fill_kernel(const int* __restrict__ ei, const float* __restrict__ w,
                            const float* __restrict__ dinv, const int* __restrict__ off,
                            const int* __restrict__ seq, int2* __restrict__ epack) {
    int e = blockIdx.x * 256 + threadIdx.x;
    if (e < N_EDGES) {
        int r = ei[e];
        int c = ei[N_EDGES + e];
        int p = off[c] + seq[e];
        float nrm = dinv[r] * w[e] * dinv[c];
        epack[p] = make_int2(r, __float_as_int(nrm));
    }
}

// ---------------- GEMM1: XW = X @ W1 (fp32 compute, fp16 store) ----------------

__global__ __launch_bounds__(256) void gemm1_kernel(const float* __restrict__ X,
                                                    const float* __restrict__ W,
                                                    __half* __restrict__ XW) {
    __shared__ float sA[32][132];   // [k][m]
    __shared__ float sB[32][132];   // [k][n] (128 used)
    int t = threadIdx.x;
    int row0 = blockIdx.x * 128;
    int tc = t & 15, tr = t >> 4;
    int m0 = tr * 8, n0 = tc * 8;
    float acc[8][8] = {};
    for (int kt = 0; kt < 128; kt += 32) {
        #pragma unroll
        for (int q = 0; q < 4; ++q) {
            int g = t + q * 256;          // 0..1023
            int row = g >> 3;
            int c4 = g & 7;
            float4 v = make_float4(0.f, 0.f, 0.f, 0.f);
            int grow = row0 + row;
            if (grow < N_NODES) v = *(const float4*)(X + (size_t)grow * 128 + kt + c4 * 4);
            sA[c4 * 4 + 0][row] = v.x;
            sA[c4 * 4 + 1][row] = v.y;
            sA[c4 * 4 + 2][row] = v.z;
            sA[c4 * 4 + 3][row] = v.w;
        }
        #pragma unroll
        for (int q = 0; q < 4; ++q) {
            int g = t + q * 256;
            int k = g >> 5, n4 = g & 31;
            *(float4*)(&sB[k][n4 * 4]) = *(const float4*)(W + (kt + k) * 128 + n4 * 4);
        }
        __syncthreads();
        #pragma unroll
        for (int k = 0; k < 32; ++k) {
            float4 a0 = *(const float4*)(&sA[k][m0]);
            float4 a1 = *(const float4*)(&sA[k][m0 + 4]);
            float4 b0 = *(const float4*)(&sB[k][n0]);
            float4 b1v = *(const float4*)(&sB[k][n0 + 4]);
            float a[8] = {a0.x, a0.y, a0.z, a0.w, a1.x, a1.y, a1.z, a1.w};
            float b[8] = {b0.x, b0.y, b0.z, b0.w, b1v.x, b1v.y, b1v.z, b1v.w};
            #pragma unroll
            for (int j = 0; j < 8; ++j)
                #pragma unroll
                for (int i = 0; i < 8; ++i) acc[j][i] += a[j] * b[i];
        }
        __syncthreads();
    }
    #pragma unroll
    for (int j = 0; j < 8; ++j) {
        int grow = row0 + m0 + j;
        if (grow < N_NODES) {
            __align__(16) __half2 hp[4];
            hp[0] = __floats2half2_rn(acc[j][0], acc[j][1]);
            hp[1] = __floats2half2_rn(acc[j][2], acc[j][3]);
            hp[2] = __floats2half2_rn(acc[j][4], acc[j][5]);
            hp[3] = __floats2half2_rn(acc[j][6], acc[j][7]);
            *(float4*)(XW + (size_t)grow * 128 + n0) = *(const float4*)hp;
        }
    }
}

// ---- Fused aggregation-1 + bias + relu + GEMM2 (fp16 gather, fp32 math) ----
// wave per node; scalar (SGPR) CSR path; split main(8-deep)/tail edge loops;
// per-wave GEMM2 tail with W2+H in LDS (fp32). Grid = N_NODES/4 exactly.

__global__ __launch_bounds__(256) void agg1f_kernel(const __half* __restrict__ XW,
                                                    const int* __restrict__ off,
                                                    const int2* __restrict__ epack,
                                                    const float* __restrict__ dinv,
                                                    const float* __restrict__ b1,
                                                    const float* __restrict__ W2,
                                                    __half* __restrict__ HW) {
    __shared__ __align__(16) float sW2[5120];   // [k][c] = k*40+c, 20 KB
    __shared__ __align__(16) float sH[4][128];  // one H row per wave
    int t = threadIdx.x;
    // stage W2 (1280 float4 / 256 threads = 5 each)
    #pragma unroll
    for (int q = 0; q < 5; ++q) {
        int g = t + q * 256;
        ((float4*)sW2)[g] = ((const float4*)W2)[g];
    }

    int wv = __builtin_amdgcn_readfirstlane(t) >> 6;   // SGPR wave index
    int n = blockIdx.x * 4 + wv;                       // uniform node id
    int l = t & 63;
    const __half2* XW2 = (const __half2*)XW;           // 64 half2 per row
    float di = dinv[n];
    float self = di * di;
    float2 v = __half22float2(XW2[(size_t)n * 64 + l]);
    float accx[8], accy[8];
    accx[0] = self * v.x; accy[0] = self * v.y;
    #pragma unroll
    for (int k = 1; k < 8; ++k) { accx[k] = 0.f; accy[k] = 0.f; }
    int e0 = off[n], e1 = off[n + 1];                  // scalar loads
    int emain = e0 + ((e1 - e0) & ~7);
    for (int base = e0; base < emain; base += 8) {
        int2 p[8];
        #pragma unroll
        for (int k = 0; k < 8; ++k) p[k] = epack[base + k];   // scalar loads
        #pragma unroll
        for (int k = 0; k < 8; ++k) {
            float2 g = __half22float2(XW2[(size_t)p[k].x * 64 + l]);
            float w = __int_as_float(p[k].y);
            accx[k] += w * g.x;
            accy[k] += w * g.y;
        }
    }
    for (int e = emain; e < e1; ++e) {
        int2 p = epack[e];
        float2 g = __half22float2(XW2[(size_t)p.x * 64 + l]);
        float w = __int_as_float(p.y);
        accx[0] += w * g.x;
        accy[0] += w * g.y;
    }
    float ax = ((accx[0] + accx[1]) + (accx[2] + accx[3])) + ((accx[4] + accx[5]) + (accx[6] + accx[7]));
    float ay = ((accy[0] + accy[1]) + (accy[2] + accy[3])) + ((accy[4] + accy[5]) + (accy[6] + accy[7]));
    float2 bb = ((const float2*)b1)[l];
    float hx = fmaxf(ax + bb.x, 0.f);
    float hy = fmaxf(ay + bb.y, 0.f);
    ((float2*)sH[wv])[l] = make_float2(hx, hy);
    __syncthreads();   // uniform: grid exactly covers N_NODES; also publishes sW2

    // per-wave GEMM2 row: lanes 0..39 each compute one output column
    if (l < 40) {
        const float* hrow = sH[wv];
        float dot = 0.f;
        #pragma unroll 4
        for (int k = 0; k < 128; k += 4) {
            float4 h4 = *(const float4*)(hrow + k);
            dot += h4.x * sW2[(k + 0) * 40 + l];
            dot += h4.y * sW2[(k + 1) * 40 + l];
            dot += h4.z * sW2[(k + 2) * 40 + l];
            dot += h4.w * sW2[(k + 3) * 40 + l];
        }
        HW[(size_t)n * 40 + l] = __float2half_rn(dot);
    }
}

// ---------------- Aggregation layer 2 (fp16 gather, scalar CSR path) + b2 + softmax ----------------

__global__ __launch_bounds__(256) void agg2_kernel(const __half* __restrict__ HW,
                                                   const int* __restrict__ off,
                                                   const int2* __restrict__ epack,
                                                   const float* __restrict__ dinv,
                                                   const float* __restrict__ b2,
                                                   float* __restrict__ out) {
    int t = threadIdx.x;
    int wv = __builtin_amdgcn_readfirstlane(t) >> 6;   // SGPR wave index
    int n = blockIdx.x * 4 + wv;                       // uniform node id
    int l = t & 63;
    if (n >= N_NODES) return;                          // uniform branch
    bool act = (l < 40);
    int ll = act ? l : l - 40;   // idle lanes mirror low features: loads stay in-row
    float di = dinv[n];
    float acc[8];
    acc[0] = di * di * __half2float(HW[(size_t)n * 40 + ll]);
    #pragma unroll
    for (int k = 1; k < 8; ++k) acc[k] = 0.f;
    int e0 = off[n], e1 = off[n + 1];
    int emain = e0 + ((e1 - e0) & ~7);
    for (int base = e0; base < emain; base += 8) {
        int2 p[8];
        #pragma unroll
        for (int k = 0; k < 8; ++k) p[k] = epack[base + k];
        #pragma unroll
        for (int k = 0; k < 8; ++k) {
            float g = __half2float(HW[(size_t)p[k].x * 40 + ll]);
            acc[k] += __int_as_float(p[k].y) * g;
        }
    }
    for (int e = emain; e < e1; ++e) {
        int2 p = epack[e];
        acc[0] += __int_as_float(p.y) * __half2float(HW[(size_t)p.x * 40 + ll]);
    }
    float a = ((acc[0] + acc[1]) + (acc[2] + acc[3])) + ((acc[4] + acc[5]) + (acc[6] + acc[7]));
    a += b2[ll];
    float m = act ? a : -1e30f;
    #pragma unroll
    for (int d = 32; d; d >>= 1) m = fmaxf(m, __shfl_xor(m, d, 64));
    float pexp = act ? expf(a - m) : 0.f;
    float s = pexp;
    #pragma unroll
    for (int d = 32; d; d >>= 1) s += __shfl_xor(s, d, 64);
    if (act) out[(size_t)n * 40 + l] = pexp / s;
}

// ---------------- launch ----------------

extern "C" void kernel_launch(void* const* d_in, const int* in_sizes, int n_in,
                              void* d_out, int out_size, void* d_ws, size_t ws_size,
                              hipStream_t stream) {
    const float* x  = (const float*)d_in[0];
    const int*   ei = (const int*)d_in[1];
    const float* ew = (const float*)d_in[2];
    // d_in[3] = attention (PERIODS=1 -> softmax = 1.0, unused)
    const float* W1 = (const float*)d_in[4];
    const float* b1 = (const float*)d_in[5];
    const float* W2 = (const float*)d_in[6];
    const float* b2 = (const float*)d_in[7];
    float* out = (float*)d_out;

    char* p = (char*)d_ws;
    auto alloc = [&](size_t bytes) -> void* {
        void* r = (void*)p;
        p += (bytes + 511) & ~(size_t)511;
        return r;
    };
    unsigned long long* packed = (unsigned long long*)alloc((size_t)N_NODES * 8);
    float* dinv   = (float*)alloc((size_t)N_NODES * 4);
    int*   off    = (int*)alloc((size_t)(N_NODES + 1) * 4);
    int*   bsum   = (int*)alloc(1024 * 4);
    int*   seq    = (int*)alloc((size_t)N_EDGES * 4);
    int2*  epack  = (int2*)alloc((size_t)N_EDGES * 8);
    __half* XW    = (__half*)alloc((size_t)N_NODES * 128 * 2);
    __half* HW    = (__half*)alloc((size_t)N_NODES * 40 * 2);

    int nblk_n = (N_NODES + 255) / 256;
    int nblk_e = (N_EDGES + 255) / 256;
    int nblk_s = (N_NODES + 1023) / 1024;   // 98

    hipLaunchKernelGGL(init_kernel,  dim3(nblk_n), dim3(256), 0, stream, packed);
    hipLaunchKernelGGL(count_kernel, dim3(nblk_e), dim3(256), 0, stream, ei, ew, packed, seq);
    hipLaunchKernelGGL(scanA_kernel, dim3(nblk_s), dim3(1024), 0, stream, packed, off, bsum, dinv);
    hipLaunchKernelGGL(scanB_kernel, dim3(1), dim3(1024), 0, stream, bsum, nblk_s);
    hipLaunchKernelGGL(scanC_kernel, dim3(nblk_s), dim3(1024), 0, stream, off, bsum);
    hipLaunchKernelGGL(fill_kernel,  dim3(nblk_e), dim3(256), 0, stream, ei, ew, dinv, off, seq, epack);

    hipLaunchKernelGGL(gemm1_kernel, dim3((N_NODES + 127) / 128), dim3(256), 0, stream, x, W1, XW);
    hipLaunchKernelGGL(agg1f_kernel, dim3(N_NODES / 4), dim3(256), 0, stream,
                       XW, off, epack, dinv, b1, W2, HW);
    hipLaunchKernelGGL(agg2_kernel,  dim3((N_NODES + 3) / 4), dim3(256), 0, stream,
                       HW, off, epack, dinv, b2, out);
}

// Round 15
// 310.302 us; speedup vs baseline: 1.3847x; 1.0891x over previous
//
#include <hip/hip_runtime.h>
#include <hip/hip_bf16.h>
#include <hip/hip_fp16.h>

#define N_NODES 100000
#define N_EDGES 1600000
#define G1_BLOCKS 782   // ceil(N_NODES/128)

// ---------------- CSR build (1 atomic per edge, packed 64-bit) ----------------

__global__ void init_kernel(unsigned long long* packed) {
    int i = blockIdx.x * 256 + threadIdx.x;
    if (i < N_NODES) packed[i] = 0ULL;
}

// ---- Fused k1: gemm1 (blocks 0..781) + count (blocks 782..7031) ----
// Independent work co-scheduled in one dispatch: gemm1 is VALU-bound,
// count is atomic-pipe bound — they overlap instead of serializing.

__global__ __launch_bounds__(256) void k1_kernel(const float* __restrict__ X,
                                                 const float* __restrict__ W,
                                                 __half* __restrict__ XW,
                                                 const int* __restrict__ ei,
                                                 const float* __restrict__ ew,
                                                 unsigned long long* packed,
                                                 int* __restrict__ seq) {
    __shared__ float sA[32][132];   // [k][m]
    __shared__ float sB[32][132];   // [k][n]
    int t = threadIdx.x;
    if (blockIdx.x >= G1_BLOCKS) {
        // ---- count body ----
        int e = (blockIdx.x - G1_BLOCKS) * 256 + t;
        if (e < N_EDGES) {
            int c = ei[N_EDGES + e];
            unsigned int fw = (unsigned int)rintf(ew[e] * 1048576.0f);
            unsigned long long old = atomicAdd(&packed[c], (1ULL << 32) | (unsigned long long)fw);
            seq[e] = (int)(old >> 32);
        }
        return;
    }
    // ---- gemm1 body ----
    int row0 = blockIdx.x * 128;
    int tc = t & 15, tr = t >> 4;
    int m0 = tr * 8, n0 = tc * 8;
    float acc[8][8] = {};
    for (int kt = 0; kt < 128; kt += 32) {
        #pragma unroll
        for (int q = 0; q < 4; ++q) {
            int g = t + q * 256;          // 0..1023
            int row = g >> 3;
            int c4 = g & 7;
            float4 v = make_float4(0.f, 0.f, 0.f, 0.f);
            int grow = row0 + row;
            if (grow < N_NODES) v = *(const float4*)(X + (size_t)grow * 128 + kt + c4 * 4);
            sA[c4 * 4 + 0][row] = v.x;
            sA[c4 * 4 + 1][row] = v.y;
            sA[c4 * 4 + 2][row] = v.z;
            sA[c4 * 4 + 3][row] = v.w;
        }
        #pragma unroll
        for (int q = 0; q < 4; ++q) {
            int g = t + q * 256;
            int k = g >> 5, n4 = g & 31;
            *(float4*)(&sB[k][n4 * 4]) = *(const float4*)(W + (kt + k) * 128 + n4 * 4);
        }
        __syncthreads();
        #pragma unroll
        for (int k = 0; k < 32; ++k) {
            float4 a0 = *(const float4*)(&sA[k][m0]);
            float4 a1 = *(const float4*)(&sA[k][m0 + 4]);
            float4 b0 = *(const float4*)(&sB[k][n0]);
            float4 b1v = *(const float4*)(&sB[k][n0 + 4]);
            float a[8] = {a0.x, a0.y, a0.z, a0.w, a1.x, a1.y, a1.z, a1.w};
            float b[8] = {b0.x, b0.y, b0.z, b0.w, b1v.x, b1v.y, b1v.z, b1v.w};
            #pragma unroll
            for (int j = 0; j < 8; ++j)
                #pragma unroll
                for (int i = 0; i < 8; ++i) acc[j][i] += a[j] * b[i];
        }
        __syncthreads();
    }
    #pragma unroll
    for (int j = 0; j < 8; ++j) {
        int grow = row0 + m0 + j;
        if (grow < N_NODES) {
            __align__(16) __half2 hp[4];
            hp[0] = __floats2half2_rn(acc[j][0], acc[j][1]);
            hp[1] = __floats2half2_rn(acc[j][2], acc[j][3]);
            hp[2] = __floats2half2_rn(acc[j][4], acc[j][5]);
            hp[3] = __floats2half2_rn(acc[j][6], acc[j][7]);
            *(float4*)(XW + (size_t)grow * 128 + n0) = *(const float4*)hp;
        }
    }
}

// per-block exclusive scan over counts (packed>>32); also computes dinv (fused)
__global__ void scanA_kernel(const unsigned long long* __restrict__ packed,
                             int* __restrict__ off, int* __restrict__ bsum,
                             float* __restrict__ dinv) {
    __shared__ int s[1024];
    int t = threadIdx.x;
    int i = blockIdx.x * 1024 + t;
    unsigned long long pk = (i < N_NODES) ? packed[i] : 0ULL;
    int v = (int)(pk >> 32);
    if (i < N_NODES) {
        float deg = 1.0f + (float)(unsigned int)(pk & 0xffffffffULL) * (1.0f / 1048576.0f);
        dinv[i] = rsqrtf(deg);
    }
    s[t] = v; __syncthreads();
    #pragma unroll
    for (int d = 1; d < 1024; d <<= 1) {
        int x = (t >= d) ? s[t - d] : 0;
        __syncthreads();
        s[t] += x;
        __syncthreads();
    }
    if (i < N_NODES) off[i] = s[t] - v;
    if (t == 1023) bsum[blockIdx.x] = s[1023];
}

__global__ void scanB_kernel(int* bsum, int nb) {
    __shared__ int s[1024];
    int t = threadIdx.x;
    int v = (t < nb) ? bsum[t] : 0;
    s[t] = v; __syncthreads();
    #pragma unroll
    for (int d = 1; d < 1024; d <<= 1) {
        int x = (t >= d) ? s[t - d] : 0;
        __syncthreads();
        s[t] += x;
        __syncthreads();
    }
    if (t < nb) bsum[t] = s[t] - v;
}

__global__ void scanC_kernel(int* __restrict__ off, const int* __restrict__ bsum) {
    int i = blockIdx.x * 1024 + threadIdx.x;
    if (i < N_NODES) off[i] += bsum[blockIdx.x];
    if (i == 0) off[N_NODES] = N_EDGES;
}

// atomic-free fill: slot = off[dst] + seq[e]
__global__ void fill_kernel(const int* __restrict__ ei, const float* __restrict__ w,
                            const float* __restrict__ dinv, const int* __restrict__ off,
                            const int* __restrict__ seq, int2* __restrict__ epack) {
    int e = blockIdx.x * 256 + threadIdx.x;
    if (e < N_EDGES) {
        int r = ei[e];
        int c = ei[N_EDGES + e];
        int p = off[c] + seq[e];
        float nrm = dinv[r] * w[e] * dinv[c];
        epack[p] = make_int2(r, __float_as_int(nrm));
    }
}

// ---- Fused aggregation-1 + bias + relu + GEMM2 (fp16 gather, fp32 math) ----
// wave per node; scalar (SGPR) CSR path; split main(8-deep)/tail edge loops;
// fp16 W2 in LDS (10 KB -> 8 blocks/CU, thread-limited occupancy 100%).

__global__ __launch_bounds__(256) void agg1f_kernel(const __half* __restrict__ XW,
                                                    const int* __restrict__ off,
                                                    const int2* __restrict__ epack,
                                                    const float* __restrict__ dinv,
                                                    const float* __restrict__ b1,
                                                    const float* __restrict__ W2,
                                                    __half* __restrict__ HW) {
    __shared__ __align__(16) __half sW2h[5120];  // [k][c] = k*40+c, 10 KB
    __shared__ __align__(16) float sH[4][128];   // one H row per wave, 2 KB
    int t = threadIdx.x;
    // stage W2 fp32->fp16 (2560 half2 / 256 threads = 10 each)
    const float2* W22 = (const float2*)W2;
    #pragma unroll
    for (int q = 0; q < 10; ++q) {
        int g = t + q * 256;
        float2 v = W22[g];
        ((__half2*)sW2h)[g] = __floats2half2_rn(v.x, v.y);
    }

    int wv = __builtin_amdgcn_readfirstlane(t) >> 6;   // SGPR wave index
    int n = blockIdx.x * 4 + wv;                       // uniform node id
    int l = t & 63;
    const __half2* XW2 = (const __half2*)XW;           // 64 half2 per row
    float di = dinv[n];
    float self = di * di;
    float2 v = __half22float2(XW2[(size_t)n * 64 + l]);
    float accx[8], accy[8];
    accx[0] = self * v.x; accy[0] = self * v.y;
    #pragma unroll
    for (int k = 1; k < 8; ++k) { accx[k] = 0.f; accy[k] = 0.f; }
    int e0 = off[n], e1 = off[n + 1];                  // scalar loads
    int emain = e0 + ((e1 - e0) & ~7);
    for (int base = e0; base < emain; base += 8) {
        int2 p[8];
        #pragma unroll
        for (int k = 0; k < 8; ++k) p[k] = epack[base + k];   // scalar loads
        #pragma unroll
        for (int k = 0; k < 8; ++k) {
            float2 g = __half22float2(XW2[(size_t)p[k].x * 64 + l]);
            float w = __int_as_float(p[k].y);
            accx[k] += w * g.x;
            accy[k] += w * g.y;
        }
    }
    for (int e = emain; e < e1; ++e) {
        int2 p = epack[e];
        float2 g = __half22float2(XW2[(size_t)p.x * 64 + l]);
        float w = __int_as_float(p.y);
        accx[0] += w * g.x;
        accy[0] += w * g.y;
    }
    float ax = ((accx[0] + accx[1]) + (accx[2] + accx[3])) + ((accx[4] + accx[5]) + (accx[6] + accx[7]));
    float ay = ((accy[0] + accy[1]) + (accy[2] + accy[3])) + ((accy[4] + accy[5]) + (accy[6] + accy[7]));
    float2 bb = ((const float2*)b1)[l];
    float hx = fmaxf(ax + bb.x, 0.f);
    float hy = fmaxf(ay + bb.y, 0.f);
    ((float2*)sH[wv])[l] = make_float2(hx, hy);
    __syncthreads();   // uniform: grid exactly covers N_NODES; also publishes sW2h

    // per-wave GEMM2 row: lanes 0..39 each compute one output column (fp32 accum)
    if (l < 40) {
        const float* hrow = sH[wv];
        float dot = 0.f;
        #pragma unroll 4
        for (int k = 0; k < 128; k += 4) {
            float4 h4 = *(const float4*)(hrow + k);
            dot += h4.x * __half2float(sW2h[(k + 0) * 40 + l]);
            dot += h4.y * __half2float(sW2h[(k + 1) * 40 + l]);
            dot += h4.z * __half2float(sW2h[(k + 2) * 40 + l]);
            dot += h4.w * __half2float(sW2h[(k + 3) * 40 + l]);
        }
        HW[(size_t)n * 40 + l] = __float2half_rn(dot);
    }
}

// ---------------- Aggregation layer 2 (fp16 gather, scalar CSR path) + b2 + softmax ----------------

__global__ __launch_bounds__(256) void agg2_kernel(const __half* __restrict__ HW,
                                                   const int* __restrict__ off,
                                                   const int2* __restrict__ epack,
                                                   const float* __restrict__ dinv,
                                                   const float* __restrict__ b2,
                                                   float* __restrict__ out) {
    int t = threadIdx.x;
    int wv = __builtin_amdgcn_readfirstlane(t) >> 6;   // SGPR wave index
    int n = blockIdx.x * 4 + wv;                       // uniform node id
    int l = t & 63;
    if (n >= N_NODES) return;                          // uniform branch
    bool act = (l < 40);
    int ll = act ? l : l - 40;   // idle lanes mirror low features: loads stay in-row
    float di = dinv[n];
    float acc[8];
    acc[0] = di * di * __half2float(HW[(size_t)n * 40 + ll]);
    #pragma unroll
    for (int k = 1; k < 8; ++k) acc[k] = 0.f;
    int e0 = off[n], e1 = off[n + 1];
    int emain = e0 + ((e1 - e0) & ~7);
    for (int base = e0; base < emain; base += 8) {
        int2 p[8];
        #pragma unroll
        for (int k = 0; k < 8; ++k) p[k] = epack[base + k];
        #pragma unroll
        for (int k = 0; k < 8; ++k) {
            float g = __half2float(HW[(size_t)p[k].x * 40 + ll]);
            acc[k] += __int_as_float(p[k].y) * g;
        }
    }
    for (int e = emain; e < e1; ++e) {
        int2 p = epack[e];
        acc[0] += __int_as_float(p.y) * __half2float(HW[(size_t)p.x * 40 + ll]);
    }
    float a = ((acc[0] + acc[1]) + (acc[2] + acc[3])) + ((acc[4] + acc[5]) + (acc[6] + acc[7]));
    a += b2[ll];
    float m = act ? a : -1e30f;
    #pragma unroll
    for (int d = 32; d; d >>= 1) m = fmaxf(m, __shfl_xor(m, d, 64));
    float pexp = act ? expf(a - m) : 0.f;
    float s = pexp;
    #pragma unroll
    for (int d = 32; d; d >>= 1) s += __shfl_xor(s, d, 64);
    if (act) out[(size_t)n * 40 + l] = pexp / s;
}

// ---------------- launch ----------------

extern "C" void kernel_launch(void* const* d_in, const int* in_sizes, int n_in,
                              void* d_out, int out_size, void* d_ws, size_t ws_size,
                              hipStream_t stream) {
    const float* x  = (const float*)d_in[0];
    const int*   ei = (const int*)d_in[1];
    const float* ew = (const float*)d_in[2];
    // d_in[3] = attention (PERIODS=1 -> softmax = 1.0, unused)
    const float* W1 = (const float*)d_in[4];
    const float* b1 = (const float*)d_in[5];
    const float* W2 = (const float*)d_in[6];
    const float* b2 = (const float*)d_in[7];
    float* out = (float*)d_out;

    char* p = (char*)d_ws;
    auto alloc = [&](size_t bytes) -> void* {
        void* r = (void*)p;
        p += (bytes + 511) & ~(size_t)511;
        return r;
    };
    unsigned long long* packed = (unsigned long long*)alloc((size_t)N_NODES * 8);
    float* dinv   = (float*)alloc((size_t)N_NODES * 4);
    int*   off    = (int*)alloc((size_t)(N_NODES + 1) * 4);
    int*   bsum   = (int*)alloc(1024 * 4);
    int*   seq    = (int*)alloc((size_t)N_EDGES * 4);
    int2*  epack  = (int2*)alloc((size_t)N_EDGES * 8);
    __half* XW    = (__half*)alloc((size_t)N_NODES * 128 * 2);
    __half* HW    = (__half*)alloc((size_t)N_NODES * 40 * 2);

    int nblk_n = (N_NODES + 255) / 256;
    int nblk_e = (N_EDGES + 255) / 256;   // 6250
    int nblk_s = (N_NODES + 1023) / 1024; // 98

    hipLaunchKernelGGL(init_kernel,  dim3(nblk_n), dim3(256), 0, stream, packed);
    hipLaunchKernelGGL(k1_kernel,    dim3(G1_BLOCKS + nblk_e), dim3(256), 0, stream,
                       x, W1, XW, ei, ew, packed, seq);
    hipLaunchKernelGGL(scanA_kernel, dim3(nblk_s), dim3(1024), 0, stream, packed, off, bsum, dinv);
    hipLaunchKernelGGL(scanB_kernel, dim3(1), dim3(1024), 0, stream, bsum, nblk_s);
    hipLaunchKernelGGL(scanC_kernel, dim3(nblk_s), dim3(1024), 0, stream, off, bsum);
    hipLaunchKernelGGL(fill_kernel,  dim3(nblk_e), dim3(256), 0, stream, ei, ew, dinv, off, seq, epack);

    hipLaunchKernelGGL(agg1f_kernel, dim3(N_NODES / 4), dim3(256), 0, stream,
                       XW, off, epack, dinv, b1, W2, HW);
    hipLaunchKernelGGL(agg2_kernel,  dim3((N_NODES + 3) / 4), dim3(256), 0, stream,
                       HW, off, epack, dinv, b2, out);
}

// Round 16
// 281.160 us; speedup vs baseline: 1.5283x; 1.1037x over previous
//
#include <hip/hip_runtime.h>
#include <hip/hip_bf16.h>
#include <hip/hip_fp16.h>

#define N_NODES 100000
#define N_EDGES 1600000
#define G1_BLOCKS 782   // ceil(N_NODES/128)

// ---------------- CSR build (1 atomic per edge, packed 64-bit) ----------------

__global__ void init_kernel(unsigned long long* packed) {
    int i = blockIdx.x * 256 + threadIdx.x;
    if (i < N_NODES) packed[i] = 0ULL;
}

// ---- Fused k1: gemm1 (blocks 0..781) + count (blocks 782..7031) ----

__global__ __launch_bounds__(256) void k1_kernel(const float* __restrict__ X,
                                                 const float* __restrict__ W,
                                                 __half* __restrict__ XW,
                                                 const int* __restrict__ ei,
                                                 const float* __restrict__ ew,
                                                 unsigned long long* packed,
                                                 int* __restrict__ seq) {
    __shared__ float sA[32][132];   // [k][m]
    __shared__ float sB[32][132];   // [k][n]
    int t = threadIdx.x;
    if (blockIdx.x >= G1_BLOCKS) {
        // ---- count body ----
        int e = (blockIdx.x - G1_BLOCKS) * 256 + t;
        if (e < N_EDGES) {
            int c = ei[N_EDGES + e];
            unsigned int fw = (unsigned int)rintf(ew[e] * 1048576.0f);
            unsigned long long old = atomicAdd(&packed[c], (1ULL << 32) | (unsigned long long)fw);
            seq[e] = (int)(old >> 32);
        }
        return;
    }
    // ---- gemm1 body ----
    int row0 = blockIdx.x * 128;
    int tc = t & 15, tr = t >> 4;
    int m0 = tr * 8, n0 = tc * 8;
    float acc[8][8] = {};
    for (int kt = 0; kt < 128; kt += 32) {
        #pragma unroll
        for (int q = 0; q < 4; ++q) {
            int g = t + q * 256;          // 0..1023
            int row = g >> 3;
            int c4 = g & 7;
            float4 v = make_float4(0.f, 0.f, 0.f, 0.f);
            int grow = row0 + row;
            if (grow < N_NODES) v = *(const float4*)(X + (size_t)grow * 128 + kt + c4 * 4);
            sA[c4 * 4 + 0][row] = v.x;
            sA[c4 * 4 + 1][row] = v.y;
            sA[c4 * 4 + 2][row] = v.z;
            sA[c4 * 4 + 3][row] = v.w;
        }
        #pragma unroll
        for (int q = 0; q < 4; ++q) {
            int g = t + q * 256;
            int k = g >> 5, n4 = g & 31;
            *(float4*)(&sB[k][n4 * 4]) = *(const float4*)(W + (kt + k) * 128 + n4 * 4);
        }
        __syncthreads();
        #pragma unroll
        for (int k = 0; k < 32; ++k) {
            float4 a0 = *(const float4*)(&sA[k][m0]);
            float4 a1 = *(const float4*)(&sA[k][m0 + 4]);
            float4 b0 = *(const float4*)(&sB[k][n0]);
            float4 b1v = *(const float4*)(&sB[k][n0 + 4]);
            float a[8] = {a0.x, a0.y, a0.z, a0.w, a1.x, a1.y, a1.z, a1.w};
            float b[8] = {b0.x, b0.y, b0.z, b0.w, b1v.x, b1v.y, b1v.z, b1v.w};
            #pragma unroll
            for (int j = 0; j < 8; ++j)
                #pragma unroll
                for (int i = 0; i < 8; ++i) acc[j][i] += a[j] * b[i];
        }
        __syncthreads();
    }
    #pragma unroll
    for (int j = 0; j < 8; ++j) {
        int grow = row0 + m0 + j;
        if (grow < N_NODES) {
            __align__(16) __half2 hp[4];
            hp[0] = __floats2half2_rn(acc[j][0], acc[j][1]);
            hp[1] = __floats2half2_rn(acc[j][2], acc[j][3]);
            hp[2] = __floats2half2_rn(acc[j][4], acc[j][5]);
            hp[3] = __floats2half2_rn(acc[j][6], acc[j][7]);
            *(float4*)(XW + (size_t)grow * 128 + n0) = *(const float4*)hp;
        }
    }
}

// per-block exclusive scan over counts (packed>>32); also computes dinv (fused)
__global__ void scanA_kernel(const unsigned long long* __restrict__ packed,
                             int* __restrict__ off, int* __restrict__ bsum,
                             float* __restrict__ dinv) {
    __shared__ int s[1024];
    int t = threadIdx.x;
    int i = blockIdx.x * 1024 + t;
    unsigned long long pk = (i < N_NODES) ? packed[i] : 0ULL;
    int v = (int)(pk >> 32);
    if (i < N_NODES) {
        float deg = 1.0f + (float)(unsigned int)(pk & 0xffffffffULL) * (1.0f / 1048576.0f);
        dinv[i] = rsqrtf(deg);
    }
    s[t] = v; __syncthreads();
    #pragma unroll
    for (int d = 1; d < 1024; d <<= 1) {
        int x = (t >= d) ? s[t - d] : 0;
        __syncthreads();
        s[t] += x;
        __syncthreads();
    }
    if (i < N_NODES) off[i] = s[t] - v;
    if (t == 1023) bsum[blockIdx.x] = s[1023];
}

__global__ void scanB_kernel(int* bsum, int nb) {
    __shared__ int s[1024];
    int t = threadIdx.x;
    int v = (t < nb) ? bsum[t] : 0;
    s[t] = v; __syncthreads();
    #pragma unroll
    for (int d = 1; d < 1024; d <<= 1) {
        int x = (t >= d) ? s[t - d] : 0;
        __syncthreads();
        s[t] += x;
        __syncthreads();
    }
    if (t < nb) bsum[t] = s[t] - v;
}

__global__ void scanC_kernel(int* __restrict__ off, const int* __restrict__ bsum) {
    int i = blockIdx.x * 1024 + threadIdx.x;
    if (i < N_NODES) off[i] += bsum[blockIdx.x];
    if (i == 0) off[N_NODES] = N_EDGES;
}

// atomic-free fill: slot = off[dst] + seq[e]
__global__ void fill_kernel(const int* __restrict__ ei, const float* __restrict__ w,
                            const float* __restrict__ dinv, const int* __restrict__ off,
                            const int* __restrict__ seq, int2* __restrict__ epack) {
    int e = blockIdx.x * 256 + threadIdx.x;
    if (e < N_EDGES) {
        int r = ei[e];
        int c = ei[N_EDGES + e];
        int p = off[c] + seq[e];
        float nrm = dinv[r] * w[e] * dinv[c];
        epack[p] = make_int2(r, __float_as_int(nrm));
    }
}

// ---- Fused aggregation-1 + bias + relu + GEMM2 (fp16 gather, fp32 math) ----
// wave per node; scalar (SGPR) CSR path; 16-deep main batches (mean degree ~16)
// + clamped 8-deep remainder; fp32 W2 in LDS (r14-proven tail, no cvt).

__global__ __launch_bounds__(256) void agg1f_kernel(const __half* __restrict__ XW,
                                                    const int* __restrict__ off,
                                                    const int2* __restrict__ epack,
                                                    const float* __restrict__ dinv,
                                                    const float* __restrict__ b1,
                                                    const float* __restrict__ W2,
                                                    __half* __restrict__ HW) {
    __shared__ __align__(16) float sW2[5120];   // [k][c] = k*40+c, 20 KB
    __shared__ __align__(16) float sH[4][128];  // one H row per wave
    int t = threadIdx.x;
    // stage W2 (1280 float4 / 256 threads = 5 each)
    #pragma unroll
    for (int q = 0; q < 5; ++q) {
        int g = t + q * 256;
        ((float4*)sW2)[g] = ((const float4*)W2)[g];
    }

    int wv = __builtin_amdgcn_readfirstlane(t) >> 6;   // SGPR wave index
    int n = blockIdx.x * 4 + wv;                       // uniform node id
    int l = t & 63;
    const __half2* XW2 = (const __half2*)XW;           // 64 half2 per row
    float di = dinv[n];
    float self = di * di;
    float2 v = __half22float2(XW2[(size_t)n * 64 + l]);
    float accx[8], accy[8];
    accx[0] = self * v.x; accy[0] = self * v.y;
    #pragma unroll
    for (int k = 1; k < 8; ++k) { accx[k] = 0.f; accy[k] = 0.f; }
    int e0 = off[n], e1 = off[n + 1];                  // scalar loads
    int base = e0;
    // 16-deep main batches: 16 gathers in flight per wave
    for (; base + 16 <= e1; base += 16) {
        int2 p[16];
        #pragma unroll
        for (int k = 0; k < 16; ++k) p[k] = epack[base + k];   // scalar loads
        #pragma unroll
        for (int k = 0; k < 16; ++k) {
            float2 g = __half22float2(XW2[(size_t)p[k].x * 64 + l]);
            float w = __int_as_float(p[k].y);
            accx[k & 7] += w * g.x;
            accy[k & 7] += w * g.y;
        }
    }
    // clamped 8-deep remainder (0..15 edges -> at most 2 iterations)
    for (; base < e1; base += 8) {
        int last = e1 - 1;
        int2 p[8];
        float w[8];
        #pragma unroll
        for (int k = 0; k < 8; ++k) {
            int e = base + k;
            int idx = min(e, last);
            p[k] = epack[idx];
            w[k] = (e < e1) ? __int_as_float(p[k].y) : 0.f;
        }
        #pragma unroll
        for (int k = 0; k < 8; ++k) {
            float2 g = __half22float2(XW2[(size_t)p[k].x * 64 + l]);
            accx[k] += w[k] * g.x;
            accy[k] += w[k] * g.y;
        }
    }
    float ax = ((accx[0] + accx[1]) + (accx[2] + accx[3])) + ((accx[4] + accx[5]) + (accx[6] + accx[7]));
    float ay = ((accy[0] + accy[1]) + (accy[2] + accy[3])) + ((accy[4] + accy[5]) + (accy[6] + accy[7]));
    float2 bb = ((const float2*)b1)[l];
    float hx = fmaxf(ax + bb.x, 0.f);
    float hy = fmaxf(ay + bb.y, 0.f);
    ((float2*)sH[wv])[l] = make_float2(hx, hy);
    __syncthreads();   // uniform: grid exactly covers N_NODES; also publishes sW2

    // per-wave GEMM2 row: lanes 0..39 each compute one output column (fp32)
    if (l < 40) {
        const float* hrow = sH[wv];
        float dot = 0.f;
        #pragma unroll 4
        for (int k = 0; k < 128; k += 4) {
            float4 h4 = *(const float4*)(hrow + k);
            dot += h4.x * sW2[(k + 0) * 40 + l];
            dot += h4.y * sW2[(k + 1) * 40 + l];
            dot += h4.z * sW2[(k + 2) * 40 + l];
            dot += h4.w * sW2[(k + 3) * 40 + l];
        }
        HW[(size_t)n * 40 + l] = __float2half_rn(dot);
    }
}

// ---------------- Aggregation layer 2 (fp16 gather, 16-deep) + b2 + softmax ----------------

__global__ __launch_bounds__(256) void agg2_kernel(const __half* __restrict__ HW,
                                                   const int* __restrict__ off,
                                                   const int2* __restrict__ epack,
                                                   const float* __restrict__ dinv,
                                                   const float* __restrict__ b2,
                                                   float* __restrict__ out) {
    int t = threadIdx.x;
    int wv = __builtin_amdgcn_readfirstlane(t) >> 6;   // SGPR wave index
    int n = blockIdx.x * 4 + wv;                       // uniform node id
    int l = t & 63;
    if (n >= N_NODES) return;                          // uniform branch
    bool act = (l < 40);
    int ll = act ? l : l - 40;   // idle lanes mirror low features: loads stay in-row
    float di = dinv[n];
    float acc[8];
    acc[0] = di * di * __half2float(HW[(size_t)n * 40 + ll]);
    #pragma unroll
    for (int k = 1; k < 8; ++k) acc[k] = 0.f;
    int e0 = off[n], e1 = off[n + 1];
    int base = e0;
    for (; base + 16 <= e1; base += 16) {
        int2 p[16];
        #pragma unroll
        for (int k = 0; k < 16; ++k) p[k] = epack[base + k];
        #pragma unroll
        for (int k = 0; k < 16; ++k) {
            float g = __half2float(HW[(size_t)p[k].x * 40 + ll]);
            acc[k & 7] += __int_as_float(p[k].y) * g;
        }
    }
    for (; base < e1; base += 8) {
        int last = e1 - 1;
        int2 p[8];
        float w[8];
        #pragma unroll
        for (int k = 0; k < 8; ++k) {
            int e = base + k;
            int idx = min(e, last);
            p[k] = epack[idx];
            w[k] = (e < e1) ? __int_as_float(p[k].y) : 0.f;
        }
        #pragma unroll
        for (int k = 0; k < 8; ++k) {
            float g = __half2float(HW[(size_t)p[k].x * 40 + ll]);
            acc[k] += w[k] * g;
        }
    }
    float a = ((acc[0] + acc[1]) + (acc[2] + acc[3])) + ((acc[4] + acc[5]) + (acc[6] + acc[7]));
    a += b2[ll];
    float m = act ? a : -1e30f;
    #pragma unroll
    for (int d = 32; d; d >>= 1) m = fmaxf(m, __shfl_xor(m, d, 64));
    float pexp = act ? expf(a - m) : 0.f;
    float s = pexp;
    #pragma unroll
    for (int d = 32; d; d >>= 1) s += __shfl_xor(s, d, 64);
    if (act) out[(size_t)n * 40 + l] = pexp / s;
}

// ---------------- launch ----------------

extern "C" void kernel_launch(void* const* d_in, const int* in_sizes, int n_in,
                              void* d_out, int out_size, void* d_ws, size_t ws_size,
                              hipStream_t stream) {
    const float* x  = (const float*)d_in[0];
    const int*   ei = (const int*)d_in[1];
    const float* ew = (const float*)d_in[2];
    // d_in[3] = attention (PERIODS=1 -> softmax = 1.0, unused)
    const float* W1 = (const float*)d_in[4];
    const float* b1 = (const float*)d_in[5];
    const float* W2 = (const float*)d_in[6];
    const float* b2 = (const float*)d_in[7];
    float* out = (float*)d_out;

    char* p = (char*)d_ws;
    auto alloc = [&](size_t bytes) -> void* {
        void* r = (void*)p;
        p += (bytes + 511) & ~(size_t)511;
        return r;
    };
    unsigned long long* packed = (unsigned long long*)alloc((size_t)N_NODES * 8);
    float* dinv   = (float*)alloc((size_t)N_NODES * 4);
    int*   off    = (int*)alloc((size_t)(N_NODES + 1) * 4);
    int*   bsum   = (int*)alloc(1024 * 4);
    int*   seq    = (int*)alloc((size_t)N_EDGES * 4);
    int2*  epack  = (int2*)alloc((size_t)N_EDGES * 8);
    __half* XW    = (__half*)alloc((size_t)N_NODES * 128 * 2);
    __half* HW    = (__half*)alloc((size_t)N_NODES * 40 * 2);

    int nblk_n = (N_NODES + 255) / 256;
    int nblk_e = (N_EDGES + 255) / 256;   // 6250
    int nblk_s = (N_NODES + 1023) / 1024; // 98

    hipLaunchKernelGGL(init_kernel,  dim3(nblk_n), dim3(256), 0, stream, packed);
    hipLaunchKernelGGL(k1_kernel,    dim3(G1_BLOCKS + nblk_e), dim3(256), 0, stream,
                       x, W1, XW, ei, ew, packed, seq);
    hipLaunchKernelGGL(scanA_kernel, dim3(nblk_s), dim3(1024), 0, stream, packed, off, bsum, dinv);
    hipLaunchKernelGGL(scanB_kernel, dim3(1), dim3(1024), 0, stream, bsum, nblk_s);
    hipLaunchKernelGGL(scanC_kernel, dim3(nblk_s), dim3(1024), 0, stream, off, bsum);
    hipLaunchKernelGGL(fill_kernel,  dim3(nblk_e), dim3(256), 0, stream, ei, ew, dinv, off, seq, epack);

    hipLaunchKernelGGL(agg1f_kernel, dim3(N_NODES / 4), dim3(256), 0, stream,
                       XW, off, epack, dinv, b1, W2, HW);
    hipLaunchKernelGGL(agg2_kernel,  dim3((N_NODES + 3) / 4), dim3(256), 0, stream,
                       HW, off, epack, dinv, b2, out);
}